// Round 6
// baseline (160.515 us; speedup 1.0000x reference)
//
#include <hip/hip_runtime.h>

#define BS 16
#define NNODES 20000
#define CIN 32
#define SEQ 9
#define COUT 64
#define KTOT 288
#define MPOOL 5000
#define NNZ 20000

#define NT 256      // nodes per block (4 waves x 64 nodes)
#define WPAD 296    // w_lds row stride bf16: 592B = 37 slots (odd) -> conflict-light frag reads

#define H_BYTES   40960000ULL   // 16*20000*64 * 2
#define XB_BYTES  20480000ULL   // 16*20000*32 * 2
#define AUX_INTS  (5000 + 5000 + 5001 + NNZ)

typedef __attribute__((ext_vector_type(8))) short bf16x8;
typedef __attribute__((ext_vector_type(4))) float f32x4;

#define CAST_G(p) ((const __attribute__((address_space(1))) void*)(p))
#define CAST_L(p) ((__attribute__((address_space(3))) void*)(p))
#define WAITV(N) asm volatile("s_waitcnt vmcnt(" #N ")" ::: "memory")
#define WAITL0() asm volatile("s_waitcnt lgkmcnt(0)" ::: "memory")

static __device__ __forceinline__ unsigned short f2bf(float f) {
  unsigned u = __float_as_uint(f);
  u += 0x7FFF + ((u >> 16) & 1);   // RNE
  return (unsigned short)(u >> 16);
}
static __device__ __forceinline__ float bf2f(unsigned short s) {
  return __uint_as_float(((unsigned)s) << 16);
}

// ---- pre-pass: x f32 -> bf16 ----
__global__ __launch_bounds__(256) void cvt_kernel(const float* __restrict__ x,
                                                  unsigned short* __restrict__ xb) {
  const size_t base = ((size_t)blockIdx.x * 256 + threadIdx.x) * 8;
  const float4 v0 = *(const float4*)(x + base);
  const float4 v1 = *(const float4*)(x + base + 4);
  uint4 p;
  p.x = (unsigned)f2bf(v0.x) | ((unsigned)f2bf(v0.y) << 16);
  p.y = (unsigned)f2bf(v0.z) | ((unsigned)f2bf(v0.w) << 16);
  p.z = (unsigned)f2bf(v1.x) | ((unsigned)f2bf(v1.y) << 16);
  p.w = (unsigned)f2bf(v1.z) | ((unsigned)f2bf(v1.w) << 16);
  *(uint4*)(xb + base) = p;
}

// ---- gemm+elu: async gather -> LDS via global_load_lds, wave-private dbuf pipeline ----
__global__ __launch_bounds__(256, 2) void gemm_elu_kernel(
    const unsigned short* __restrict__ xb,  // [BS][NNODES][CIN] bf16
    const int* __restrict__ indices,        // [NNODES][SEQ]
    const float* __restrict__ weight,       // [COUT][KTOT]
    const float* __restrict__ bias,         // [COUT]
    unsigned short* __restrict__ h)         // [BS][NNODES][COUT] bf16
{
  __shared__ unsigned short w_lds[COUT * WPAD];      // 37888 bf16 = 75776 B.. (37.9 KB)
  __shared__ unsigned short a_ring[2 * NT * CIN];    // 2 x 16 KB
  __shared__ unsigned short idx_lds[NT * SEQ];       // u16 indices, 4.6 KB

  // XCD-affinity swizzle: each XCD owns 2 batches -> xb working set ~2.6 MB/XCD (L2-fits)
  const int id = blockIdx.x;
  const int xcd = id & 7;
  const int slot0 = id >> 3;
  const int b = xcd * 2 + (slot0 & 1);
  const int n0 = (slot0 >> 1) * NT;
  const int tid = threadIdx.x;

  // stage weight (64x288 f32 -> bf16)
  for (int i = tid; i < COUT * (KTOT / 4); i += 256) {
    const float4 wv4 = ((const float4*)weight)[i];
    const int o = i / (KTOT / 4);
    const int k4 = (i % (KTOT / 4)) * 4;
    unsigned p0 = (unsigned)f2bf(wv4.x) | ((unsigned)f2bf(wv4.y) << 16);
    unsigned p1 = (unsigned)f2bf(wv4.z) | ((unsigned)f2bf(wv4.w) << 16);
    *(uint2*)&w_lds[o * WPAD + k4] = make_uint2(p0, p1);
  }
  // stage spiral indices as u16 (values < 20000 fit)
  for (int i = tid; i < NT * SEQ; i += 256) {
    const int gidx = n0 * SEQ + i;
    idx_lds[i] = (gidx < NNODES * SEQ) ? (unsigned short)indices[gidx] : (unsigned short)0;
  }
  __syncthreads();

  const int wv = tid >> 6;
  const int lane = tid & 63;
  const int l16 = lane & 15;
  const int lhi = lane >> 4;
  const unsigned short* __restrict__ xb_b = xb + (size_t)b * NNODES * CIN;

  // staging geometry: wave wv stages its own 64 rows (4 issues x 16 rows).
  // LDS slot s = wv*256 + i*64 + lane holds (row = wv*64+i*16+(lane>>2),
  // cb' = lane&3); data cb = cb' ^ ((row>>1)&3)  [16B-slot swizzle, src-side]
  const int srow_base = wv * 64 + (lane >> 2);
  const int scb = ((lane & 3) ^ ((lane >> 3) & 3)) * 8;   // bf16 offset in row

  auto stage = [&](int kk, int sl) {
#pragma unroll
    for (int i = 0; i < 4; ++i) {
      const int srow = srow_base + i * 16;
      const int gi = (int)idx_lds[srow * SEQ + kk];
      const unsigned short* src = xb_b + (size_t)gi * CIN + scb;
      unsigned short* dst = &a_ring[sl * (NT * CIN) + wv * 2048 + i * 512];  // wave-uniform
      __builtin_amdgcn_global_load_lds(CAST_G(src), CAST_L(dst), 16, 0, 0);
    }
  };

  f32x4 acc[4][4];
#pragma unroll
  for (int a = 0; a < 4; ++a)
#pragma unroll
    for (int o = 0; o < 4; ++o) {
      f32x4 z = {0.f, 0.f, 0.f, 0.f};
      acc[a][o] = z;
    }

  const int acbswz = (lhi ^ ((l16 >> 1) & 3)) << 3;  // read-side swizzled cb offset (bf16)

  // prologue: chunks 0,1 in flight (8 issues outstanding per wave)
  stage(0, 0);
  stage(1, 1);

#define CHUNK(KK, VM)                                                              \
  do {                                                                             \
    WAITV(VM);                                                                     \
    bf16x8 af[4], bfr[4];                                                          \
    _Pragma("unroll") for (int a2 = 0; a2 < 4; ++a2) {                             \
      const int arow = wv * 64 + a2 * 16 + l16;                                    \
      af[a2] = *(const bf16x8*)&a_ring[((KK)&1) * (NT * CIN) + arow * CIN + acbswz]; \
      bfr[a2] = *(const bf16x8*)&w_lds[(a2 * 16 + l16) * WPAD + (KK) * 32 + lhi * 8]; \
    }                                                                              \
    WAITL0();                                                                      \
    if ((KK) + 2 < SEQ) stage((KK) + 2, (KK)&1);                                   \
    _Pragma("unroll") for (int a2 = 0; a2 < 4; ++a2)                               \
      _Pragma("unroll") for (int o2 = 0; o2 < 4; ++o2)                             \
        acc[a2][o2] = __builtin_amdgcn_mfma_f32_16x16x32_bf16(af[a2], bfr[o2],     \
                                                              acc[a2][o2], 0, 0, 0); \
  } while (0)

  CHUNK(0, 4);
  CHUNK(1, 4);
  CHUNK(2, 4);
  CHUNK(3, 4);
  CHUNK(4, 4);
  CHUNK(5, 4);
  CHUNK(6, 4);
  CHUNK(7, 4);
  CHUNK(8, 0);
#undef CHUNK

  // epilogue: bias + elu -> h bf16.  D layout: col=lane&15, row=(lane>>4)*4+reg
#pragma unroll
  for (int o = 0; o < 4; ++o) {
    const int oc = o * 16 + l16;
    const float bv = bias[oc];
#pragma unroll
    for (int a = 0; a < 4; ++a) {
#pragma unroll
      for (int r = 0; r < 4; ++r) {
        const int node = n0 + wv * 64 + a * 16 + lhi * 4 + r;
        if (node < NNODES) {
          float vvv = acc[a][o][r] + bv;
          vvv = vvv > 0.f ? vvv : expm1f(vvv);
          h[((size_t)b * NNODES + node) * COUT + oc] = f2bf(vvv);
        }
      }
    }
  }
}

// ---- CSR build ----
__global__ __launch_bounds__(256) void hist_kernel(const int* __restrict__ rows,
                                                   int* __restrict__ cnt) {
  const int k = blockIdx.x * 256 + threadIdx.x;
  if (k < NNZ) atomicAdd(&cnt[rows[k]], 1);
}

__global__ __launch_bounds__(256) void scan_kernel(const int* __restrict__ cnt,
                                                   int* __restrict__ start) {
  __shared__ int part[256];
  const int t = threadIdx.x;
  const int base = t * 20;
  int local[20];
  int s = 0;
#pragma unroll
  for (int j = 0; j < 20; ++j) {
    const int i = base + j;
    local[j] = s;
    s += (i < MPOOL) ? cnt[i] : 0;
  }
  part[t] = s;
  __syncthreads();
  for (int off = 1; off < 256; off <<= 1) {
    const int v = (t >= off) ? part[t - off] : 0;
    __syncthreads();
    part[t] += v;
    __syncthreads();
  }
  const int excl = (t == 0) ? 0 : part[t - 1];
#pragma unroll
  for (int j = 0; j < 20; ++j) {
    const int i = base + j;
    if (i < MPOOL) start[i] = excl + local[j];
  }
  if (t == 255) start[MPOOL] = part[255];
}

__global__ __launch_bounds__(256) void reorder_kernel(const int* __restrict__ rows,
                                                      const int* __restrict__ start,
                                                      int* __restrict__ cursor,
                                                      int* __restrict__ csr) {
  const int k = blockIdx.x * 256 + threadIdx.x;
  if (k < NNZ) {
    const int r = rows[k];
    const int pos = atomicAdd(&cursor[r], 1);
    csr[start[r] + pos] = k;
  }
}

// ---- pool: one wave per (row, b), atomic-free, XCD b-affinity ----
__global__ __launch_bounds__(256) void pool_kernel(
    const unsigned short* __restrict__ h,   // [BS][NNODES][COUT] bf16
    const int* __restrict__ cols,
    const float* __restrict__ vals,
    const int* __restrict__ start,
    const int* __restrict__ csr,
    float* __restrict__ out)                // [BS][MPOOL][COUT]
{
  const int id = blockIdx.x;                // 20000 blocks
  const int xcd = id & 7;
  const int slot = id >> 3;                 // 0..2499
  const int b = xcd * 2 + (slot & 1);
  const int rg = slot >> 1;                 // 0..1249
  const int wv = (int)(threadIdx.x >> 6);
  const int lane = (int)(threadIdx.x & 63);
  const int r = rg * 4 + wv;

  const int s = start[r];
  const int e = start[r + 1];
  float acc = 0.f;
  for (int j = s; j < e; ++j) {
    const int k = csr[j];
    const int c = cols[k];
    const float v = vals[k];
    acc += v * bf2f(h[((size_t)b * NNODES + c) * COUT + lane]);
  }
  out[((size_t)b * MPOOL + r) * COUT + lane] = acc;
}

// ---- fallback atomic scatter (small ws) ----
__global__ __launch_bounds__(256) void scatter_kernel(
    const unsigned short* __restrict__ h,
    const int* __restrict__ rows,
    const int* __restrict__ cols,
    const float* __restrict__ vals,
    float* __restrict__ out)
{
  const int gw = (int)((blockIdx.x * blockDim.x + threadIdx.x) >> 6);
  const int lane = threadIdx.x & 63;
  const int nw = (int)((gridDim.x * blockDim.x) >> 6);
  for (int t = gw; t < NNZ * BS; t += nw) {
    const int k = t >> 4;
    const int b = t & 15;
    const float hv = bf2f(h[((size_t)b * NNODES + cols[k]) * COUT + lane]);
    atomicAdd(&out[((size_t)b * MPOOL + rows[k]) * COUT + lane], hv * vals[k]);
  }
}

extern "C" void kernel_launch(void* const* d_in, const int* in_sizes, int n_in,
                              void* d_out, int out_size, void* d_ws, size_t ws_size,
                              hipStream_t stream) {
  const float* x       = (const float*)d_in[0];
  const int*   indices = (const int*)d_in[1];
  const float* weight  = (const float*)d_in[2];
  const float* bias    = (const float*)d_in[3];
  const int*   trows   = (const int*)d_in[4];
  const int*   tcols   = (const int*)d_in[5];
  const float* tvals   = (const float*)d_in[6];
  float* out = (float*)d_out;

  unsigned short* h  = (unsigned short*)d_ws;
  unsigned short* xb = (unsigned short*)((char*)d_ws + H_BYTES);
  int* aux    = (int*)((char*)d_ws + H_BYTES + XB_BYTES);
  int* cnt    = aux;                 // [5000]
  int* cursor = aux + 5000;          // [5000]
  int* start  = aux + 10000;         // [5001]
  int* csr    = aux + 15001;         // [20000]

  const bool big_ws = (ws_size >= H_BYTES + XB_BYTES + AUX_INTS * sizeof(int));

  cvt_kernel<<<(BS * NNODES * CIN) / (256 * 8), 256, 0, stream>>>(x, xb);
  gemm_elu_kernel<<<1264, 256, 0, stream>>>(xb, indices, weight, bias, h);

  if (big_ws) {
    hipMemsetAsync(cnt, 0, 10000 * sizeof(int), stream);   // cnt + cursor
    hist_kernel<<<(NNZ + 255) / 256, 256, 0, stream>>>(trows, cnt);
    scan_kernel<<<1, 256, 0, stream>>>(cnt, start);
    reorder_kernel<<<(NNZ + 255) / 256, 256, 0, stream>>>(trows, start, cursor, csr);
    pool_kernel<<<20000, 256, 0, stream>>>(h, tcols, tvals, start, csr, out);
  } else {
    hipMemsetAsync(d_out, 0, (size_t)out_size * sizeof(float), stream);
    scatter_kernel<<<4096, 256, 0, stream>>>(h, trows, tcols, tvals, out);
  }
}

// Round 7
// 100.453 us; speedup vs baseline: 1.5979x; 1.5979x over previous
//
#include <hip/hip_runtime.h>

#define BS 16
#define NNODES 20000
#define CIN 32
#define SEQ 9
#define COUT 64
#define KTOT 288
#define MPOOL 5000
#define NNZ 20000

#define NTN 16       // nodes per gemm block -> 256 M-rows (node x batch)
#define WPAD 296     // w row stride (bf16)

#define H_BYTES   40960000ULL   // hT [20000][16][64] bf16
#define XB_BYTES  20480000ULL   // xbT [20000][16][32] bf16
#define WBF_BYTES ((size_t)(COUT * WPAD * 2))   // 37888
#define AUX_INTS  (5000 + 5000 + 5001 + NNZ)

typedef __attribute__((ext_vector_type(8))) short bf16x8;
typedef __attribute__((ext_vector_type(4))) float f32x4;

#define CAST_G(p) ((const __attribute__((address_space(1))) void*)(p))
#define CAST_L(p) ((__attribute__((address_space(3))) void*)(p))
#define WAITV(N) asm volatile("s_waitcnt vmcnt(" #N ")" ::: "memory")
#define WAITL0() asm volatile("s_waitcnt lgkmcnt(0)" ::: "memory")

static __device__ __forceinline__ unsigned short f2bf(float f) {
  unsigned u = __float_as_uint(f);
  u += 0x7FFF + ((u >> 16) & 1);   // RNE
  return (unsigned short)(u >> 16);
}
static __device__ __forceinline__ float bf2f(unsigned short s) {
  return __uint_as_float(((unsigned)s) << 16);
}

// ---- transpose+convert: x[b][n][c] f32 -> xbT[n][b][c] bf16 (1KB per node) ----
__global__ __launch_bounds__(256) void cvtx_kernel(const float* __restrict__ x,
                                                   unsigned short* __restrict__ xbT) {
  const int wv = threadIdx.x >> 6, lane = threadIdx.x & 63;
  const int n = blockIdx.x * 4 + wv;
  const int b = lane >> 2, c8 = (lane & 3) * 8;
  const float* src = x + ((size_t)b * NNODES + n) * CIN + c8;
  const float4 u0 = ((const float4*)src)[0];
  const float4 u1 = ((const float4*)src)[1];
  uint4 p;
  p.x = (unsigned)f2bf(u0.x) | ((unsigned)f2bf(u0.y) << 16);
  p.y = (unsigned)f2bf(u0.z) | ((unsigned)f2bf(u0.w) << 16);
  p.z = (unsigned)f2bf(u1.x) | ((unsigned)f2bf(u1.y) << 16);
  p.w = (unsigned)f2bf(u1.z) | ((unsigned)f2bf(u1.w) << 16);
  *(uint4*)&xbT[(size_t)n * 512 + (size_t)lane * 8] = p;   // n*512 + b*32 + c8
}

// ---- weight f32 -> padded bf16 [64][WPAD], one-time ----
__global__ __launch_bounds__(256) void cvtw_kernel(const float* __restrict__ weight,
                                                   unsigned short* __restrict__ wbf) {
  const int i = blockIdx.x * 256 + threadIdx.x;
  if (i < COUT * (KTOT / 4)) {
    const float4 wv4 = ((const float4*)weight)[i];
    const int o = i / (KTOT / 4);
    const int k4 = (i % (KTOT / 4)) * 4;
    unsigned p0 = (unsigned)f2bf(wv4.x) | ((unsigned)f2bf(wv4.y) << 16);
    unsigned p1 = (unsigned)f2bf(wv4.z) | ((unsigned)f2bf(wv4.w) << 16);
    *(uint2*)&wbf[o * WPAD + k4] = make_uint2(p0, p1);
  }
}

// ---- gemm+elu: M = (node,b), gathers are 1KB-contiguous global_load_lds ----
__global__ __launch_bounds__(256, 2) void gemm_elu_kernel(
    const unsigned short* __restrict__ xbT,  // [NNODES][16][32] bf16
    const int* __restrict__ indices,         // [NNODES][SEQ]
    const unsigned short* __restrict__ wbf,  // [64][WPAD] bf16
    const float* __restrict__ bias,          // [COUT]
    unsigned short* __restrict__ hT)         // [NNODES][16][64] bf16
{
  __shared__ unsigned short w_lds[COUT * WPAD];   // 37888 B
  __shared__ unsigned short a_ring[2 * 256 * CIN];// 32768 B
  __shared__ int idx_lds[NTN * SEQ];              // 576 B

  const int n0 = blockIdx.x * NTN;
  const int tid = threadIdx.x;

  // copy pre-converted weight (flat 16B chunks)
  for (int i = tid; i < (COUT * WPAD) / 8; i += 256)
    ((uint4*)w_lds)[i] = ((const uint4*)wbf)[i];
  if (tid < NTN * SEQ) idx_lds[tid] = indices[n0 * SEQ + tid];
  __syncthreads();

  const int wv = tid >> 6;
  const int lane = tid & 63;
  const int l16 = lane & 15;
  const int lhi = lane >> 4;

  // staging: one instruction stages one node's 16 batch-rows (1KB contiguous).
  // src chunk swizzle key = (b>>1)&3  (b = lane>>2), read key = (l16>>1)&3.
  const int srcoff = (lane >> 2) * 32 + (((lane & 3) ^ ((lane >> 3) & 3)) * 8);

  auto stage = [&](int kk, int sl) {
#pragma unroll
    for (int i = 0; i < 4; ++i) {
      const int nl = wv * 4 + i;
      const int gi = idx_lds[nl * SEQ + kk];
      const unsigned short* src = xbT + (size_t)gi * 512 + srcoff;
      unsigned short* dst = &a_ring[sl * 8192 + nl * 512];   // wave-uniform base
      __builtin_amdgcn_global_load_lds(CAST_G(src), CAST_L(dst), 16, 0, 0);
    }
  };

  f32x4 acc[4][4];
#pragma unroll
  for (int a = 0; a < 4; ++a)
#pragma unroll
    for (int o = 0; o < 4; ++o) {
      f32x4 z = {0.f, 0.f, 0.f, 0.f};
      acc[a][o] = z;
    }

  const int acbswz = (lhi ^ ((l16 >> 1) & 3)) * 8;  // read-side swizzled chunk (bf16 units)

  stage(0, 0);
  stage(1, 1);

#define CHUNK(KK, VM)                                                               \
  do {                                                                              \
    WAITV(VM);                                                                      \
    bf16x8 af[4], bfr[4];                                                           \
    _Pragma("unroll") for (int a2 = 0; a2 < 4; ++a2) {                              \
      af[a2] = *(const bf16x8*)&a_ring[((KK)&1) * 8192 +                            \
                                       (wv * 64 + a2 * 16 + l16) * CIN + acbswz];   \
      bfr[a2] = *(const bf16x8*)&w_lds[(a2 * 16 + l16) * WPAD + (KK) * 32 + lhi * 8]; \
    }                                                                               \
    WAITL0();                                                                       \
    if ((KK) + 2 < SEQ) stage((KK) + 2, (KK)&1);                                    \
    _Pragma("unroll") for (int a2 = 0; a2 < 4; ++a2)                                \
      _Pragma("unroll") for (int o2 = 0; o2 < 4; ++o2)                              \
        acc[a2][o2] = __builtin_amdgcn_mfma_f32_16x16x32_bf16(af[a2], bfr[o2],      \
                                                              acc[a2][o2], 0, 0, 0); \
  } while (0)

  CHUNK(0, 4);
  CHUNK(1, 4);
  CHUNK(2, 4);
  CHUNK(3, 4);
  CHUNK(4, 4);
  CHUNK(5, 4);
  CHUNK(6, 4);
  CHUNK(7, 4);
  CHUNK(8, 0);
#undef CHUNK

  // epilogue: D row = (lhi*4+r) = batch, tile a = node; col = oc
#pragma unroll
  for (int o = 0; o < 4; ++o) {
    const int oc = o * 16 + l16;
    const float bv = bias[oc];
#pragma unroll
    for (int a = 0; a < 4; ++a) {
      const int node = n0 + wv * 4 + a;
#pragma unroll
      for (int r = 0; r < 4; ++r) {
        const int b = lhi * 4 + r;
        float vvv = acc[a][o][r] + bv;
        vvv = vvv > 0.f ? vvv : expm1f(vvv);
        hT[((size_t)node * 16 + b) * COUT + oc] = f2bf(vvv);
      }
    }
  }
}

// ---- CSR build ----
__global__ __launch_bounds__(256) void hist_kernel(const int* __restrict__ rows,
                                                   int* __restrict__ cnt) {
  const int k = blockIdx.x * 256 + threadIdx.x;
  if (k < NNZ) atomicAdd(&cnt[rows[k]], 1);
}

__global__ __launch_bounds__(256) void scan_kernel(const int* __restrict__ cnt,
                                                   int* __restrict__ start) {
  __shared__ int part[256];
  const int t = threadIdx.x;
  const int base = t * 20;
  int local[20];
  int s = 0;
#pragma unroll
  for (int j = 0; j < 20; ++j) {
    const int i = base + j;
    local[j] = s;
    s += (i < MPOOL) ? cnt[i] : 0;
  }
  part[t] = s;
  __syncthreads();
  for (int off = 1; off < 256; off <<= 1) {
    const int v = (t >= off) ? part[t - off] : 0;
    __syncthreads();
    part[t] += v;
    __syncthreads();
  }
  const int excl = (t == 0) ? 0 : part[t - 1];
#pragma unroll
  for (int j = 0; j < 20; ++j) {
    const int i = base + j;
    if (i < MPOOL) start[i] = excl + local[j];
  }
  if (t == 255) start[MPOOL] = part[255];
}

__global__ __launch_bounds__(256) void reorder_kernel(const int* __restrict__ rows,
                                                      const int* __restrict__ start,
                                                      int* __restrict__ cursor,
                                                      int* __restrict__ csr) {
  const int k = blockIdx.x * 256 + threadIdx.x;
  if (k < NNZ) {
    const int r = rows[k];
    const int pos = atomicAdd(&cursor[r], 1);
    csr[start[r] + pos] = k;
  }
}

// ---- pool: wave per row; each nnz entry reads hT[c] = 2KB contiguous ----
__global__ __launch_bounds__(256) void pool_kernel(
    const unsigned short* __restrict__ hT,  // [NNODES][16][64] bf16
    const int* __restrict__ cols,
    const float* __restrict__ vals,
    const int* __restrict__ start,
    const int* __restrict__ csr,
    float* __restrict__ out)                // [BS][MPOOL][COUT]
{
  const int r = blockIdx.x * 4 + (threadIdx.x >> 6);   // grid 1250
  const int lane = threadIdx.x & 63;

  float acc[16];
#pragma unroll
  for (int b = 0; b < 16; ++b) acc[b] = 0.f;

  const int s = start[r], e = start[r + 1];
  for (int j = s; j < e; ++j) {
    const int k = csr[j];
    const int c = cols[k];
    const float v = vals[k];
    const unsigned short* hp = hT + (size_t)c * 1024 + lane;
#pragma unroll
    for (int b = 0; b < 16; ++b) acc[b] += v * bf2f(hp[b * 64]);
  }
#pragma unroll
  for (int b = 0; b < 16; ++b)
    out[((size_t)b * MPOOL + r) * COUT + lane] = acc[b];
}

// ---- fallback atomic scatter (small ws) ----
__global__ __launch_bounds__(256) void scatter_kernel(
    const unsigned short* __restrict__ hT,
    const int* __restrict__ rows,
    const int* __restrict__ cols,
    const float* __restrict__ vals,
    float* __restrict__ out)
{
  const int gw = (int)((blockIdx.x * blockDim.x + threadIdx.x) >> 6);
  const int lane = threadIdx.x & 63;
  const int nw = (int)((gridDim.x * blockDim.x) >> 6);
  for (int t = gw; t < NNZ * BS; t += nw) {
    const int k = t >> 4;
    const int b = t & 15;
    const float hv = bf2f(hT[((size_t)cols[k] * 16 + b) * COUT + lane]);
    atomicAdd(&out[((size_t)b * MPOOL + rows[k]) * COUT + lane], hv * vals[k]);
  }
}

extern "C" void kernel_launch(void* const* d_in, const int* in_sizes, int n_in,
                              void* d_out, int out_size, void* d_ws, size_t ws_size,
                              hipStream_t stream) {
  const float* x       = (const float*)d_in[0];
  const int*   indices = (const int*)d_in[1];
  const float* weight  = (const float*)d_in[2];
  const float* bias    = (const float*)d_in[3];
  const int*   trows   = (const int*)d_in[4];
  const int*   tcols   = (const int*)d_in[5];
  const float* tvals   = (const float*)d_in[6];
  float* out = (float*)d_out;

  unsigned short* hT  = (unsigned short*)d_ws;
  unsigned short* xbT = (unsigned short*)((char*)d_ws + H_BYTES);
  unsigned short* wbf = (unsigned short*)((char*)d_ws + H_BYTES + XB_BYTES);
  int* aux    = (int*)((char*)d_ws + H_BYTES + XB_BYTES + WBF_BYTES);
  int* cnt    = aux;                 // [5000]
  int* cursor = aux + 5000;          // [5000]
  int* start  = aux + 10000;         // [5001]
  int* csr    = aux + 15001;         // [20000]

  const bool big_ws =
      (ws_size >= H_BYTES + XB_BYTES + WBF_BYTES + AUX_INTS * sizeof(int));

  cvtx_kernel<<<NNODES / 4, 256, 0, stream>>>(x, xbT);
  cvtw_kernel<<<(COUT * (KTOT / 4) + 255) / 256, 256, 0, stream>>>(weight, wbf);
  gemm_elu_kernel<<<NNODES / NTN, 256, 0, stream>>>(xbT, indices, wbf, bias, hT);

  if (big_ws) {
    hipMemsetAsync(cnt, 0, 10000 * sizeof(int), stream);   // cnt + cursor
    hist_kernel<<<(NNZ + 255) / 256, 256, 0, stream>>>(trows, cnt);
    scan_kernel<<<1, 256, 0, stream>>>(cnt, start);
    reorder_kernel<<<(NNZ + 255) / 256, 256, 0, stream>>>(trows, start, cursor, csr);
    pool_kernel<<<MPOOL / 4, 256, 0, stream>>>(hT, tcols, tvals, start, csr, out);
  } else {
    hipMemsetAsync(d_out, 0, (size_t)out_size * sizeof(float), stream);
    scatter_kernel<<<4096, 256, 0, stream>>>(hT, trows, tcols, tvals, out);
  }
}

// Round 8
// 90.421 us; speedup vs baseline: 1.7752x; 1.1109x over previous
//
#include <hip/hip_runtime.h>

#define BS 16
#define NNODES 20000
#define CIN 32
#define SEQ 9
#define COUT 64
#define KTOT 288
#define MPOOL 5000
#define NNZ 20000

#define NTN 16       // nodes per gemm block -> 256 M-rows (node x batch)
#define WPAD 296     // wbf row stride (bf16), 592B = 16B-aligned rows

#define H_BYTES   40960000ULL   // hT [20000][64][16] bf16
#define XB_BYTES  20480000ULL   // xbT [20000][16][32] bf16
#define WBF_BYTES ((size_t)(COUT * WPAD * 2))   // 37888
#define AUX_INTS  (5000 + 5000 + 5001 + NNZ)

typedef __attribute__((ext_vector_type(8))) short bf16x8;
typedef __attribute__((ext_vector_type(4))) float f32x4;

static __device__ __forceinline__ unsigned short f2bf(float f) {
  unsigned u = __float_as_uint(f);
  u += 0x7FFF + ((u >> 16) & 1);   // RNE
  return (unsigned short)(u >> 16);
}
static __device__ __forceinline__ float bf2f(unsigned short s) {
  return __uint_as_float(((unsigned)s) << 16);
}

// ---- transpose+convert: x[b][n][c] f32 -> xbT[n][b][c] bf16 (1KB per node) ----
__global__ __launch_bounds__(256) void cvtx_kernel(const float* __restrict__ x,
                                                   unsigned short* __restrict__ xbT) {
  const int wv = threadIdx.x >> 6, lane = threadIdx.x & 63;
  const int n = blockIdx.x * 4 + wv;
  const int b = lane >> 2, c8 = (lane & 3) * 8;
  const float* src = x + ((size_t)b * NNODES + n) * CIN + c8;
  const float4 u0 = ((const float4*)src)[0];
  const float4 u1 = ((const float4*)src)[1];
  uint4 p;
  p.x = (unsigned)f2bf(u0.x) | ((unsigned)f2bf(u0.y) << 16);
  p.y = (unsigned)f2bf(u0.z) | ((unsigned)f2bf(u0.w) << 16);
  p.z = (unsigned)f2bf(u1.x) | ((unsigned)f2bf(u1.y) << 16);
  p.w = (unsigned)f2bf(u1.z) | ((unsigned)f2bf(u1.w) << 16);
  *(uint4*)&xbT[(size_t)n * 512 + (size_t)lane * 8] = p;   // n*512 + b*32 + c8
}

// ---- weight f32 -> padded bf16 [64][WPAD], one-time ----
__global__ __launch_bounds__(256) void cvtw_kernel(const float* __restrict__ weight,
                                                   unsigned short* __restrict__ wbf) {
  const int i = blockIdx.x * 256 + threadIdx.x;
  if (i < COUT * (KTOT / 4)) {
    const float4 wv4 = ((const float4*)weight)[i];
    const int o = i / (KTOT / 4);
    const int k4 = (i % (KTOT / 4)) * 4;
    unsigned p0 = (unsigned)f2bf(wv4.x) | ((unsigned)f2bf(wv4.y) << 16);
    unsigned p1 = (unsigned)f2bf(wv4.z) | ((unsigned)f2bf(wv4.w) << 16);
    *(uint2*)&wbf[o * WPAD + k4] = make_uint2(p0, p1);
  }
}

// ---- gemm+elu: LDS-free; A-fragments are coalesced 16B/lane global loads ----
__global__ __launch_bounds__(256, 4) void gemm_elu_kernel(
    const unsigned short* __restrict__ xbT,  // [NNODES][16][32] bf16
    const int* __restrict__ indices,         // [NNODES][SEQ]
    const unsigned short* __restrict__ wbf,  // [64][WPAD] bf16
    const float* __restrict__ bias,          // [COUT]
    unsigned short* __restrict__ hT)         // [NNODES][64][16] bf16
{
  __shared__ int idx_lds[NTN * SEQ];   // 576 B

  const int n0 = blockIdx.x * NTN;
  const int tid = threadIdx.x;
  if (tid < NTN * SEQ) idx_lds[tid] = indices[n0 * SEQ + tid];
  __syncthreads();

  const int wv = tid >> 6;
  const int lane = tid & 63;
  const int l16 = lane & 15;
  const int lhi = lane >> 4;

  // A-fragment offset inside a node's 1KB block: b=l16 (row), c=lhi*8 (k-slice)
  const int aoff = l16 * 32 + lhi * 8;   // bf16 units; wave covers full 1KB coalesced

  f32x4 acc[4][4];
#pragma unroll
  for (int a = 0; a < 4; ++a)
#pragma unroll
    for (int o = 0; o < 4; ++o) {
      f32x4 z = {0.f, 0.f, 0.f, 0.f};
      acc[a][o] = z;
    }

#pragma unroll
  for (int kk = 0; kk < SEQ; ++kk) {
    bf16x8 af[4], bfr[4];
#pragma unroll
    for (int a2 = 0; a2 < 4; ++a2) {
      const int gi = idx_lds[(wv * 4 + a2) * SEQ + kk];
      af[a2] = *(const bf16x8*)&xbT[(size_t)gi * 512 + aoff];
    }
#pragma unroll
    for (int o = 0; o < 4; ++o)
      bfr[o] = *(const bf16x8*)&wbf[(o * 16 + l16) * WPAD + kk * 32 + lhi * 8];
#pragma unroll
    for (int a2 = 0; a2 < 4; ++a2)
#pragma unroll
      for (int o2 = 0; o2 < 4; ++o2)
        acc[a2][o2] = __builtin_amdgcn_mfma_f32_16x16x32_bf16(af[a2], bfr[o2],
                                                              acc[a2][o2], 0, 0, 0);
  }

  // epilogue: bias + elu -> hT[node][oc][b], packed 8B stores
  // D: col(oc-part)=l16, row(b) = lhi*4 + r, tile a = node-local
#pragma unroll
  for (int o = 0; o < 4; ++o) {
    const int oc = o * 16 + l16;
    const float bv = bias[oc];
#pragma unroll
    for (int a = 0; a < 4; ++a) {
      const int node = n0 + wv * 4 + a;
      float v0 = acc[a][o][0] + bv, v1 = acc[a][o][1] + bv;
      float v2 = acc[a][o][2] + bv, v3 = acc[a][o][3] + bv;
      v0 = v0 > 0.f ? v0 : expm1f(v0);
      v1 = v1 > 0.f ? v1 : expm1f(v1);
      v2 = v2 > 0.f ? v2 : expm1f(v2);
      v3 = v3 > 0.f ? v3 : expm1f(v3);
      uint2 p;
      p.x = (unsigned)f2bf(v0) | ((unsigned)f2bf(v1) << 16);
      p.y = (unsigned)f2bf(v2) | ((unsigned)f2bf(v3) << 16);
      *(uint2*)&hT[(size_t)node * 1024 + oc * 16 + lhi * 4] = p;
    }
  }
}

// ---- CSR build ----
__global__ __launch_bounds__(256) void hist_kernel(const int* __restrict__ rows,
                                                   int* __restrict__ cnt) {
  const int k = blockIdx.x * 256 + threadIdx.x;
  if (k < NNZ) atomicAdd(&cnt[rows[k]], 1);
}

__global__ __launch_bounds__(256) void scan_kernel(const int* __restrict__ cnt,
                                                   int* __restrict__ start) {
  __shared__ int part[256];
  const int t = threadIdx.x;
  const int base = t * 20;
  int local[20];
  int s = 0;
#pragma unroll
  for (int j = 0; j < 20; ++j) {
    const int i = base + j;
    local[j] = s;
    s += (i < MPOOL) ? cnt[i] : 0;
  }
  part[t] = s;
  __syncthreads();
  for (int off = 1; off < 256; off <<= 1) {
    const int v = (t >= off) ? part[t - off] : 0;
    __syncthreads();
    part[t] += v;
    __syncthreads();
  }
  const int excl = (t == 0) ? 0 : part[t - 1];
#pragma unroll
  for (int j = 0; j < 20; ++j) {
    const int i = base + j;
    if (i < MPOOL) start[i] = excl + local[j];
  }
  if (t == 255) start[MPOOL] = part[255];
}

__global__ __launch_bounds__(256) void reorder_kernel(const int* __restrict__ rows,
                                                      const int* __restrict__ start,
                                                      int* __restrict__ cursor,
                                                      int* __restrict__ csr) {
  const int k = blockIdx.x * 256 + threadIdx.x;
  if (k < NNZ) {
    const int r = rows[k];
    const int pos = atomicAdd(&cursor[r], 1);
    csr[start[r] + pos] = k;
  }
}

// ---- pool: wave per row; each nnz reads hT[c] as 32B/lane contiguous ----
__global__ __launch_bounds__(256) void pool_kernel(
    const unsigned short* __restrict__ hT,  // [NNODES][64][16] bf16
    const int* __restrict__ cols,
    const float* __restrict__ vals,
    const int* __restrict__ start,
    const int* __restrict__ csr,
    float* __restrict__ out)                // [BS][MPOOL][COUT]
{
  const int r = blockIdx.x * 4 + (threadIdx.x >> 6);   // grid 1250
  const int lane = threadIdx.x & 63;                   // lane = oc

  float acc[16];
#pragma unroll
  for (int b = 0; b < 16; ++b) acc[b] = 0.f;

  const int s = start[r], e = start[r + 1];
  for (int j = s; j < e; ++j) {
    const int k = csr[j];
    const int c = cols[k];
    const float v = vals[k];
    const unsigned short* hp = hT + (size_t)c * 1024 + lane * 16;
    const bf16x8 h0 = *(const bf16x8*)hp;
    const bf16x8 h1 = *(const bf16x8*)(hp + 8);
#pragma unroll
    for (int b = 0; b < 8; ++b) {
      acc[b]     += v * bf2f((unsigned short)h0[b]);
      acc[b + 8] += v * bf2f((unsigned short)h1[b]);
    }
  }
#pragma unroll
  for (int b = 0; b < 16; ++b)
    out[((size_t)b * MPOOL + r) * COUT + lane] = acc[b];
}

// ---- fallback atomic scatter (small ws) ----
__global__ __launch_bounds__(256) void scatter_kernel(
    const unsigned short* __restrict__ hT,
    const int* __restrict__ rows,
    const int* __restrict__ cols,
    const float* __restrict__ vals,
    float* __restrict__ out)
{
  const int gw = (int)((blockIdx.x * blockDim.x + threadIdx.x) >> 6);
  const int lane = threadIdx.x & 63;
  const int nw = (int)((gridDim.x * blockDim.x) >> 6);
  for (int t = gw; t < NNZ * BS; t += nw) {
    const int k = t >> 4;
    const int b = t & 15;
    const float hv = bf2f(hT[(size_t)cols[k] * 1024 + lane * 16 + b]);
    atomicAdd(&out[((size_t)b * MPOOL + rows[k]) * COUT + lane], hv * vals[k]);
  }
}

extern "C" void kernel_launch(void* const* d_in, const int* in_sizes, int n_in,
                              void* d_out, int out_size, void* d_ws, size_t ws_size,
                              hipStream_t stream) {
  const float* x       = (const float*)d_in[0];
  const int*   indices = (const int*)d_in[1];
  const float* weight  = (const float*)d_in[2];
  const float* bias    = (const float*)d_in[3];
  const int*   trows   = (const int*)d_in[4];
  const int*   tcols   = (const int*)d_in[5];
  const float* tvals   = (const float*)d_in[6];
  float* out = (float*)d_out;

  unsigned short* hT  = (unsigned short*)d_ws;
  unsigned short* xbT = (unsigned short*)((char*)d_ws + H_BYTES);
  unsigned short* wbf = (unsigned short*)((char*)d_ws + H_BYTES + XB_BYTES);
  int* aux    = (int*)((char*)d_ws + H_BYTES + XB_BYTES + WBF_BYTES);
  int* cnt    = aux;                 // [5000]
  int* cursor = aux + 5000;          // [5000]
  int* start  = aux + 10000;         // [5001]
  int* csr    = aux + 15001;         // [20000]

  const bool big_ws =
      (ws_size >= H_BYTES + XB_BYTES + WBF_BYTES + AUX_INTS * sizeof(int));

  cvtx_kernel<<<NNODES / 4, 256, 0, stream>>>(x, xbT);
  cvtw_kernel<<<(COUT * (KTOT / 4) + 255) / 256, 256, 0, stream>>>(weight, wbf);
  gemm_elu_kernel<<<NNODES / NTN, 256, 0, stream>>>(xbT, indices, wbf, bias, hT);

  if (big_ws) {
    hipMemsetAsync(cnt, 0, 10000 * sizeof(int), stream);   // cnt + cursor
    hist_kernel<<<(NNZ + 255) / 256, 256, 0, stream>>>(trows, cnt);
    scan_kernel<<<1, 256, 0, stream>>>(cnt, start);
    reorder_kernel<<<(NNZ + 255) / 256, 256, 0, stream>>>(trows, start, cursor, csr);
    pool_kernel<<<MPOOL / 4, 256, 0, stream>>>(hT, tcols, tvals, start, csr, out);
  } else {
    hipMemsetAsync(d_out, 0, (size_t)out_size * sizeof(float), stream);
    scatter_kernel<<<4096, 256, 0, stream>>>(hT, trows, tcols, tvals, out);
  }
}

// Round 9
// 82.334 us; speedup vs baseline: 1.9495x; 1.0982x over previous
//
#include <hip/hip_runtime.h>

#define BS 16
#define NNODES 20000
#define CIN 32
#define SEQ 9
#define COUT 64
#define KTOT 288
#define MPOOL 5000
#define NNZ 20000

#define H_BYTES   40960000ULL   // hT [20000][64][16] bf16
#define XB_BYTES  20480000ULL   // xbT [20000][16][32] bf16
#define WF_BYTES  ((size_t)(SEQ * 4 * 512 * 2))   // 73728 B, fragment-ordered weight
#define AUX_INTS  (5001 + NNZ)                    // start[5001] + csr[20000]

typedef __attribute__((ext_vector_type(8))) short bf16x8;
typedef __attribute__((ext_vector_type(4))) float f32x4;

static __device__ __forceinline__ unsigned short f2bf(float f) {
  unsigned u = __float_as_uint(f);
  u += 0x7FFF + ((u >> 16) & 1);   // RNE
  return (unsigned short)(u >> 16);
}
static __device__ __forceinline__ float bf2f(unsigned short s) {
  return __uint_as_float(((unsigned)s) << 16);
}

// ---- prep: x[b][n][c] f32 -> xbT[n][b][c] bf16 (blocks <5000)
//      and weight -> wf[kk][o][lane*8] fragment-ordered bf16 (blocks >=5000) ----
__global__ __launch_bounds__(256) void prep_kernel(const float* __restrict__ x,
                                                   const float* __restrict__ weight,
                                                   unsigned short* __restrict__ xbT,
                                                   unsigned short* __restrict__ wf) {
  const int id = blockIdx.x;
  if (id < NNODES / 4) {
    const int wv = threadIdx.x >> 6, lane = threadIdx.x & 63;
    const int n = id * 4 + wv;
    const int b = lane >> 2, c8 = (lane & 3) * 8;
    const float* src = x + ((size_t)b * NNODES + n) * CIN + c8;
    const float4 u0 = ((const float4*)src)[0];
    const float4 u1 = ((const float4*)src)[1];
    uint4 p;
    p.x = (unsigned)f2bf(u0.x) | ((unsigned)f2bf(u0.y) << 16);
    p.y = (unsigned)f2bf(u0.z) | ((unsigned)f2bf(u0.w) << 16);
    p.z = (unsigned)f2bf(u1.x) | ((unsigned)f2bf(u1.y) << 16);
    p.w = (unsigned)f2bf(u1.z) | ((unsigned)f2bf(u1.w) << 16);
    *(uint4*)&xbT[(size_t)n * 512 + (size_t)lane * 8] = p;
  } else {
    // weight fragment layout: wf[(kk*4+o)*512 + lhi*128 + l16*8 + e] = W[o*16+l16][kk*32+lhi*8+e]
    const int t = (id - NNODES / 4) * 256 + threadIdx.x;   // 0..4607
    if (t < SEQ * 4 * 64) {
      const int f0 = t * 8;
      const int blk = f0 >> 9;          // kk*4+o
      const int inb = f0 & 511;
      const int lhi = inb >> 7;
      const int l16 = (inb >> 3) & 15;
      const int kk = blk >> 2, o = blk & 3;
      const int oc = o * 16 + l16;
      const int k0 = kk * 32 + lhi * 8;
      const float* src = weight + (size_t)oc * KTOT + k0;
      const float4 u0 = ((const float4*)src)[0];
      const float4 u1 = ((const float4*)src)[1];
      uint4 p;
      p.x = (unsigned)f2bf(u0.x) | ((unsigned)f2bf(u0.y) << 16);
      p.y = (unsigned)f2bf(u0.z) | ((unsigned)f2bf(u0.w) << 16);
      p.z = (unsigned)f2bf(u1.x) | ((unsigned)f2bf(u1.y) << 16);
      p.w = (unsigned)f2bf(u1.z) | ((unsigned)f2bf(u1.w) << 16);
      *(uint4*)&wf[f0] = p;
    }
  }
}

// ---- gemm+elu: 2 nodes/wave, scalar idx, coalesced A(1KB) + B(1KB) loads ----
__global__ __launch_bounds__(256, 5) void gemm_elu_kernel(
    const unsigned short* __restrict__ xbT,  // [NNODES][16][32] bf16
    const int* __restrict__ indices,         // [NNODES][SEQ]
    const unsigned short* __restrict__ wf,   // [SEQ*4][512] bf16 fragment-ordered
    const float* __restrict__ bias,          // [COUT]
    unsigned short* __restrict__ hT)         // [NNODES][64][16] bf16
{
  const int tid = threadIdx.x;
  const int wv = __builtin_amdgcn_readfirstlane(tid >> 6);
  const int lane = tid & 63;
  const int l16 = lane & 15;
  const int lhi = lane >> 4;
  const int n0 = blockIdx.x * 8 + wv * 2;    // wave owns nodes n0, n0+1

  const int aoff = l16 * 32 + lhi * 8;       // A frag: row=b=l16, k-slice=lhi
  const int boff = lane * 8;                 // B frag: contiguous 1KB block

  const int* __restrict__ ip = indices + (size_t)n0 * SEQ;   // wave-uniform

  f32x4 acc[2][4];
#pragma unroll
  for (int a = 0; a < 2; ++a)
#pragma unroll
    for (int o = 0; o < 4; ++o) {
      f32x4 z = {0.f, 0.f, 0.f, 0.f};
      acc[a][o] = z;
    }

#pragma unroll
  for (int kk = 0; kk < SEQ; ++kk) {
    bf16x8 af[2], bfr[4];
#pragma unroll
    for (int a = 0; a < 2; ++a) {
      const int gi = ip[a * SEQ + kk];       // s_load (uniform)
      af[a] = *(const bf16x8*)&xbT[(size_t)gi * 512 + aoff];
    }
#pragma unroll
    for (int o = 0; o < 4; ++o)
      bfr[o] = *(const bf16x8*)&wf[(kk * 4 + o) * 512 + boff];
#pragma unroll
    for (int a = 0; a < 2; ++a)
#pragma unroll
      for (int o = 0; o < 4; ++o)
        acc[a][o] = __builtin_amdgcn_mfma_f32_16x16x32_bf16(af[a], bfr[o],
                                                            acc[a][o], 0, 0, 0);
  }

  // epilogue: bias + elu -> hT[node][oc][b], 8B packed stores
  // D: col=l16 (oc part), row b = lhi*4 + reg
#pragma unroll
  for (int o = 0; o < 4; ++o) {
    const int oc = o * 16 + l16;
    const float bv = bias[oc];
#pragma unroll
    for (int a = 0; a < 2; ++a) {
      const int node = n0 + a;
      float v0 = acc[a][o][0] + bv, v1 = acc[a][o][1] + bv;
      float v2 = acc[a][o][2] + bv, v3 = acc[a][o][3] + bv;
      v0 = v0 > 0.f ? v0 : expm1f(v0);
      v1 = v1 > 0.f ? v1 : expm1f(v1);
      v2 = v2 > 0.f ? v2 : expm1f(v2);
      v3 = v3 > 0.f ? v3 : expm1f(v3);
      uint2 p;
      p.x = (unsigned)f2bf(v0) | ((unsigned)f2bf(v1) << 16);
      p.y = (unsigned)f2bf(v2) | ((unsigned)f2bf(v3) << 16);
      *(uint2*)&hT[(size_t)node * 1024 + oc * 16 + lhi * 4] = p;
    }
  }
}

// ---- CSR build: hist + scan + reorder in ONE single-block kernel ----
__global__ __launch_bounds__(1024) void csr_build_kernel(const int* __restrict__ rows,
                                                         int* __restrict__ start,
                                                         int* __restrict__ csr) {
  __shared__ int lcnt[MPOOL];   // 20 KB; later reused as cursor
  __shared__ int part[1024];
  const int t = threadIdx.x;
  for (int i = t; i < MPOOL; i += 1024) lcnt[i] = 0;
  __syncthreads();
  for (int k = t; k < NNZ; k += 1024) atomicAdd(&lcnt[rows[k]], 1);
  __syncthreads();
  // scan: 5 contiguous per thread + Hillis-Steele over partials
  int local[5];
  int s = 0;
  const int base = t * 5;
#pragma unroll
  for (int j = 0; j < 5; ++j) {
    const int i = base + j;
    local[j] = s;
    s += (i < MPOOL) ? lcnt[i] : 0;
  }
  part[t] = s;
  __syncthreads();
  for (int off = 1; off < 1024; off <<= 1) {
    const int v = (t >= off) ? part[t - off] : 0;
    __syncthreads();
    part[t] += v;
    __syncthreads();
  }
  const int excl = (t == 0) ? 0 : part[t - 1];
  __syncthreads();
#pragma unroll
  for (int j = 0; j < 5; ++j) {
    const int i = base + j;
    if (i < MPOOL) {
      const int sv = excl + local[j];
      lcnt[i] = sv;            // becomes cursor
      start[i] = sv;
    }
  }
  if (t == 0) start[MPOOL] = NNZ;
  __syncthreads();
  for (int k = t; k < NNZ; k += 1024) {
    const int r = rows[k];
    const int pos = atomicAdd(&lcnt[r], 1);
    csr[pos] = k;
  }
}

// ---- pool: wave per row; each nnz reads hT[c] as 32B/lane contiguous ----
__global__ __launch_bounds__(256) void pool_kernel(
    const unsigned short* __restrict__ hT,  // [NNODES][64][16] bf16
    const int* __restrict__ cols,
    const float* __restrict__ vals,
    const int* __restrict__ start,
    const int* __restrict__ csr,
    float* __restrict__ out)                // [BS][MPOOL][COUT]
{
  const int r = blockIdx.x * 4 + (threadIdx.x >> 6);   // grid 1250
  const int lane = threadIdx.x & 63;                   // lane = oc

  float acc[16];
#pragma unroll
  for (int b = 0; b < 16; ++b) acc[b] = 0.f;

  const int s = start[r], e = start[r + 1];
  for (int j = s; j < e; ++j) {
    const int k = csr[j];
    const int c = cols[k];
    const float v = vals[k];
    const unsigned short* hp = hT + (size_t)c * 1024 + lane * 16;
    const bf16x8 h0 = *(const bf16x8*)hp;
    const bf16x8 h1 = *(const bf16x8*)(hp + 8);
#pragma unroll
    for (int b = 0; b < 8; ++b) {
      acc[b]     += v * bf2f((unsigned short)h0[b]);
      acc[b + 8] += v * bf2f((unsigned short)h1[b]);
    }
  }
#pragma unroll
  for (int b = 0; b < 16; ++b)
    out[((size_t)b * MPOOL + r) * COUT + lane] = acc[b];
}

// ---- fallback atomic scatter (small ws) ----
__global__ __launch_bounds__(256) void scatter_kernel(
    const unsigned short* __restrict__ hT,
    const int* __restrict__ rows,
    const int* __restrict__ cols,
    const float* __restrict__ vals,
    float* __restrict__ out)
{
  const int gw = (int)((blockIdx.x * blockDim.x + threadIdx.x) >> 6);
  const int lane = threadIdx.x & 63;
  const int nw = (int)((gridDim.x * blockDim.x) >> 6);
  for (int t = gw; t < NNZ * BS; t += nw) {
    const int k = t >> 4;
    const int b = t & 15;
    const float hv = bf2f(hT[(size_t)cols[k] * 1024 + lane * 16 + b]);
    atomicAdd(&out[((size_t)b * MPOOL + rows[k]) * COUT + lane], hv * vals[k]);
  }
}

extern "C" void kernel_launch(void* const* d_in, const int* in_sizes, int n_in,
                              void* d_out, int out_size, void* d_ws, size_t ws_size,
                              hipStream_t stream) {
  const float* x       = (const float*)d_in[0];
  const int*   indices = (const int*)d_in[1];
  const float* weight  = (const float*)d_in[2];
  const float* bias    = (const float*)d_in[3];
  const int*   trows   = (const int*)d_in[4];
  const int*   tcols   = (const int*)d_in[5];
  const float* tvals   = (const float*)d_in[6];
  float* out = (float*)d_out;

  unsigned short* hT  = (unsigned short*)d_ws;
  unsigned short* xbT = (unsigned short*)((char*)d_ws + H_BYTES);
  unsigned short* wf  = (unsigned short*)((char*)d_ws + H_BYTES + XB_BYTES);
  int* aux   = (int*)((char*)d_ws + H_BYTES + XB_BYTES + WF_BYTES);
  int* start = aux;            // [5001]
  int* csr   = aux + 5001;     // [20000]

  const bool big_ws =
      (ws_size >= H_BYTES + XB_BYTES + WF_BYTES + AUX_INTS * sizeof(int));

  prep_kernel<<<NNODES / 4 + 18, 256, 0, stream>>>(x, weight, xbT, wf);
  if (big_ws) csr_build_kernel<<<1, 1024, 0, stream>>>(trows, start, csr);
  gemm_elu_kernel<<<NNODES / 8, 256, 0, stream>>>(xbT, indices, wf, bias, hT);

  if (big_ws) {
    pool_kernel<<<MPOOL / 4, 256, 0, stream>>>(hT, tcols, tvals, start, csr, out);
  } else {
    hipMemsetAsync(d_out, 0, (size_t)out_size * sizeof(float), stream);
    scatter_kernel<<<4096, 256, 0, stream>>>(hT, trows, tcols, tvals, out);
  }
}